// Round 1
// baseline (281.178 us; speedup 1.0000x reference)
//
#include <hip/hip_runtime.h>
#include <hip/hip_bf16.h>
#include <hip/hip_fp16.h>

#define NPOS 784
#define WDIM 28

typedef _Float16 f16x8 __attribute__((ext_vector_type(8)));
typedef float    f32x4 __attribute__((ext_vector_type(4)));

// ---------------- kernel 1: merged embed + qkv + out bias-init ----------------
// Blocks 0..1567: fused 1x1-conv q/k/v. Q,K fp32 [bh][kl][m]; V as f16 MFMA
//                 B-fragments [bh][s][lane][8] (lane = (kk>>3)<<4 | m, j = kk&7).
// Block 1568: embedding-MLP tables Etr/Etc (transposed [m][110]).
// Block 1569: zero the Vfrag key-pad region (keys 784..799).
__global__ __launch_bounds__(256) void prep_kernel(
    const float* __restrict__ x,
    const float* __restrict__ wq, const float* __restrict__ bq,
    const float* __restrict__ wk, const float* __restrict__ bk,
    const float* __restrict__ wv, const float* __restrict__ bv,
    const float* __restrict__ b_out,
    const float* __restrict__ rw1, const float* __restrict__ rb1,
    const float* __restrict__ rga, const float* __restrict__ rbe,
    const float* __restrict__ rw2, const float* __restrict__ rb2,
    const float* __restrict__ cw1, const float* __restrict__ cb1,
    const float* __restrict__ cga, const float* __restrict__ cbe,
    const float* __restrict__ cw2, const float* __restrict__ cb2,
    float* __restrict__ Q, float* __restrict__ K, _Float16* __restrict__ Vfrag,
    float* __restrict__ Etr, float* __restrict__ Etc,
    float* __restrict__ out)
{
    if (blockIdx.x == 1568) {                        // ---- embed path ----
        int t = threadIdx.x;
        int d = -1;
        const float *w1 = rw1, *b1 = rb1, *ga = rga, *be = rbe, *w2 = rw2, *b2 = rb2;
        float* E = Etr;
        if (t < 110) { d = t; }
        else if (t >= 128 && t < 238) { d = t - 128; w1 = cw1; b1 = cb1; ga = cga; be = cbe; w2 = cw2; b2 = cb2; E = Etc; }
        if (d < 0) return;
        float u = (d < 55) ? (-1.0f + (float)d * (2.0f / 54.0f))
                           : -(-1.0f + (float)(d - 55) * (2.0f / 54.0f));
        float hb[16], mu = 0.0f;
#pragma unroll
        for (int c = 0; c < 16; ++c) { hb[c] = u * w1[c] + b1[c]; mu += hb[c]; }
        mu *= (1.0f / 16.0f);
        float var = 0.0f;
#pragma unroll
        for (int c = 0; c < 16; ++c) { float dv = hb[c] - mu; var += dv * dv; }
        var *= (1.0f / 16.0f);
        float rstd = rsqrtf(var + 1e-5f);
#pragma unroll
        for (int c = 0; c < 16; ++c) {
            float hn = ga[c] * (hb[c] - mu) * rstd + be[c];
            hb[c] = hn / (1.0f + __expf(-hn));
        }
#pragma unroll
        for (int m = 0; m < 8; ++m) {
            float e = b2[m];
#pragma unroll
            for (int c = 0; c < 16; ++c) e += hb[c] * w2[m * 16 + c];
            E[m * 110 + d] = e;
        }
        return;
    }

    if (blockIdx.x == 1569) {                        // ---- Vfrag pad-zero path ----
        // keys 784..799 -> s=24, fragment-lanes 32..63, all j: zero so that
        // pad-P (=0) x pad-V can never produce 0*garbage = NaN in the MFMA.
        unsigned int* pz = (unsigned int*)Vfrag;
        for (int e = threadIdx.x; e < 4096; e += 256) {
            int bh = e >> 7;                         // 128 uints per bh
            int r  = e & 127;                        // (lane-32) = r>>2, j-pair = r&3
            pz[(((bh * 25 + 24) * 64 + 32 + (r >> 2)) << 2) + (r & 3)] = 0u;
        }
        return;
    }

    // ---- qkv path ----
    int idx = blockIdx.x * 256 + threadIdx.x;        // covers exactly 401408
    int ij = idx % NPOS;
    int oc = (idx / NPOS) & 127;
    int b  = idx / (NPOS * 128);

    float x0 = x[(b * 3 + 0) * NPOS + ij];
    float x1 = x[(b * 3 + 1) * NPOS + ij];
    float x2 = x[(b * 3 + 2) * NPOS + ij];

    float q = bq[oc] + wq[oc*3+0]*x0 + wq[oc*3+1]*x1 + wq[oc*3+2]*x2;
    float k = bk[oc] + wk[oc*3+0]*x0 + wk[oc*3+1]*x1 + wk[oc*3+2]*x2;
    float v = bv[oc] + wv[oc*3+0]*x0 + wv[oc*3+1]*x1 + wv[oc*3+2]*x2;

    int m = oc >> 3, h = oc & 7;                     // oc = m*HEADS + h
    int dst = ((b * 8 + h) * NPOS + ij) * 16 + m;
    Q[dst] = q; K[dst] = k;

    // V in MFMA B-fragment order: B[k][m], lane = (kslot>>3)<<4 | m, j = kslot&7
    {
        int s5 = ij >> 5, kk = ij & 31;
        int fl = ((kk >> 3) << 4) | m;
        Vfrag[((((b * 8 + h) * 25 + s5) * 64 + fl) << 3) + (kk & 7)] = (_Float16)v;
    }

    for (int e = idx; e < 4 * 64 * 4 * NPOS; e += 401408) {
        int o = (e / (4 * NPOS)) & 63;
        out[e] = b_out[o];
    }
}

// ---------------- kernel 2: attention, one head per wave ----------------
// Grid = (b, ij, head-group): 6272 blocks. Changes vs r15-base:
// pass C (PV) is now 25x v_mfma_f32_16x16x32_f16 instead of ~1080 scalar
// VALU ops + 128-shfl reduction: P lives in LDS as [g][800] f16 planes
// (A-fragment = one predicated ds_read_b128), V comes from global as
// prebuilt f16 B-fragments (perfectly coalesced lane*16B dwordx4).
__global__ __launch_bounds__(256, 5) void attn_kernel(
    const float* __restrict__ Q, const float* __restrict__ K,
    const _Float16* __restrict__ Vfrag,
    const float* __restrict__ Etr, const float* __restrict__ Etc,
    const float* __restrict__ w_out,
    float* __restrict__ out)
{
    __shared__ float4 RtE[4][56];                    // exp'ed rotation terms per wave
    __shared__ __align__(16) _Float16 ptile[4][3200];// [wave][g*800 + k], keys padded to 800
    __shared__ float ovs[4][4][16];                  // [wave(h4)][g][m]

    const int t    = threadIdx.x;
    const int wave = t >> 6, lane = t & 63;
    // XCD-aware decode: low bits round-robin (b, ij-parity) across XCDs
    const int bid = blockIdx.x;
    const int b   = (bid >> 1) & 3;
    const int r   = bid >> 3;
    const int hg  = r & 1;
    const int ij  = (r >> 1) * 2 + (bid & 1);
    const int iq  = ij / WDIM, jq = ij % WDIM;
    const int h   = hg * 4 + wave;
    const int bh  = b * 8 + h;
    const float scale = 0.57735026918962576f;        // 1/sqrt(CIN=3)

    // q in registers (wave-uniform loads, L2-hot)
    float q[16];
    {
        const float4* qp = (const float4*)(Q + (size_t)(bh * NPOS + ij) * 16);
        float4 q0 = qp[0], q1 = qp[1], q2 = qp[2], q3 = qp[3];
        q[0]=q0.x; q[1]=q0.y; q[2]=q0.z; q[3]=q0.w;
        q[4]=q1.x; q[5]=q1.y; q[6]=q1.z; q[7]=q1.w;
        q[8]=q2.x; q[9]=q2.y; q[10]=q2.z; q[11]=q2.w;
        q[12]=q3.x; q[13]=q3.y; q[14]=q3.z; q[15]=q3.w;
    }

    // rotation terms from global tables -> exp'ed
    {
        float4 mine = make_float4(-3.0e38f, -3.0e38f, -3.0e38f, -3.0e38f);
        float4 rv   = mine;
        if (lane < 55) {
            float ar = 0, ac = 0, ar5 = 0, ac5 = 0;
#pragma unroll
            for (int mm = 0; mm < 8; ++mm) {
                float ql = q[mm], qh = q[8 + mm];
                ar  += ql * Etr[mm * 110 + lane];
                ar5 += ql * Etr[mm * 110 + lane + 55];
                ac  += qh * Etc[mm * 110 + lane];
                ac5 += qh * Etc[mm * 110 + lane + 55];
            }
            rv = make_float4(ar * scale, ac * scale, ar5 * scale, ac5 * scale);
            mine = rv;
        }
#pragma unroll
        for (int off = 1; off < 64; off <<= 1) {
            mine.x = fmaxf(mine.x, __shfl_xor(mine.x, off, 64));
            mine.y = fmaxf(mine.y, __shfl_xor(mine.y, off, 64));
            mine.z = fmaxf(mine.z, __shfl_xor(mine.z, off, 64));
            mine.w = fmaxf(mine.w, __shfl_xor(mine.w, off, 64));
        }
        if (lane < 55)
            RtE[wave][lane] = make_float4(__expf(rv.x - mine.x), __expf(rv.y - mine.y),
                                          __expf(rv.z - mine.z), __expf(rv.w - mine.w));
    }

    // pass A: content in registers; track max
    float creg[13];
    float maxc = -3.0e38f;
#pragma unroll
    for (int it = 0; it < 13; ++it) {
        int k = it * 64 + lane;
        creg[it] = 0.0f;
        if (k < NPOS) {
            const float4* kp = (const float4*)(K + (size_t)(bh * NPOS + k) * 16);
            float4 k0 = kp[0], k1 = kp[1], k2 = kp[2], k3 = kp[3];
            float c = q[0]*k0.x + q[1]*k0.y + q[2]*k0.z + q[3]*k0.w
                    + q[4]*k1.x + q[5]*k1.y + q[6]*k1.z + q[7]*k1.w
                    + q[8]*k2.x + q[9]*k2.y + q[10]*k2.z + q[11]*k2.w
                    + q[12]*k3.x + q[13]*k3.y + q[14]*k3.z + q[15]*k3.w;
            creg[it] = c * scale;
            maxc = fmaxf(maxc, creg[it]);
        }
    }
#pragma unroll
    for (int off = 1; off < 64; off <<= 1) maxc = fmaxf(maxc, __shfl_xor(maxc, off, 64));

    // pass B: p once per (key,g); ps accumulated from register-resident f32 p;
    // f16 p stored to per-g planes [g][800] (keys 784..799 zero-padded).
    float ps0 = 0, ps1 = 0, ps2 = 0, ps3 = 0;
#pragma unroll
    for (int it = 0; it < 13; ++it) {
        int k = it * 64 + lane;
        float p0 = 0.0f, p1 = 0.0f, p2 = 0.0f, p3 = 0.0f;
        if (k < NPOS) {
            float ec = __expf(creg[it] - maxc);
            int rk = (k * 2341) >> 16;               // k / 28 (exact for k < 784)
            int ck = k - rk * WDIM;
            float4 er = RtE[wave][rk - iq + 27];
            float4 el = RtE[wave][ck - jq + 27];
            p0 = ec * er.x * el.y;
            p1 = ec * er.y * el.z;
            p2 = ec * er.z * el.w;
            p3 = ec * er.w * el.x;
            ps0 += p0; ps1 += p1; ps2 += p2; ps3 += p3;
        }
        if (k < 800) {                               // pad keys write exact zeros
            _Float16* dstp = &ptile[wave][k];
            dstp[0]    = (_Float16)p0;
            dstp[800]  = (_Float16)p1;
            dstp[1600] = (_Float16)p2;
            dstp[2400] = (_Float16)p3;
        }
    }
#pragma unroll
    for (int off = 1; off < 64; off <<= 1) {
        ps0 += __shfl_xor(ps0, off, 64); ps1 += __shfl_xor(ps1, off, 64);
        ps2 += __shfl_xor(ps2, off, 64); ps3 += __shfl_xor(ps3, off, 64);
    }

    // pass C (PV) as MFMA: out[g][m] = sum_k P[g][k] * V[k][m], K padded to 800.
    // A (rows 0..3 = g, rows 4..15 = 0): lane holds A[lane&15][(lane>>4)*8+j]
    //   -> one predicated ds_read_b128 from ptile per step.
    // B: lane holds B[(lane>>4)*8+j][lane&15] -> prebuilt Vfrag, lane*16B coalesced.
    // D (verified layout): col=lane&15, row=(lane>>4)*4+reg -> lanes 0..15, reg=g.
    {
        const int g15 = lane & 15, kg = lane >> 4;
        const _Float16* ap = &ptile[wave][g15 * 800 + kg * 8]; // valid when g15 < 4
        const f16x8* vp = (const f16x8*)(Vfrag + ((size_t)bh * 25 * 64 + lane) * 8);
        f32x4 d = {0.0f, 0.0f, 0.0f, 0.0f};
#pragma unroll 5
        for (int s = 0; s < 25; ++s) {
            f16x8 a = {};
            if (g15 < 4) a = *(const f16x8*)(ap + s * 32);
            f16x8 bf = vp[s * 64];                   // +512 halves per step
            d = __builtin_amdgcn_mfma_f32_16x16x32_f16(a, bf, d, 0, 0, 0);
        }
        if (kg == 0) {                               // lanes 0..15: col m = lane
            float i0 = 1.0f / ps0, i1 = 1.0f / ps1, i2 = 1.0f / ps2, i3 = 1.0f / ps3;
            ovs[wave][0][g15] = d[0] * i0;
            ovs[wave][1][g15] = d[1] * i1;
            ovs[wave][2][g15] = d[2] * i2;
            ovs[wave][3][g15] = d[3] * i3;
        }
    }
    __syncthreads();                                 // this block's 4 heads ready

    // partial output projection over 4 heads; thread = (o = t>>2, g = t&3)
    {
        int o = t >> 2, g = t & 3;
        float a = 0.0f;
#pragma unroll
        for (int m = 0; m < 16; ++m) {
            float4 w4 = *(const float4*)(w_out + o * 128 + m * 8 + hg * 4);
            a += w4.x * ovs[0][g][m] + w4.y * ovs[1][g][m]
               + w4.z * ovs[2][g][m] + w4.w * ovs[3][g][m];
        }
        atomicAdd(out + ((size_t)(b * 64 + o) * 4 + g) * NPOS + ij, a);
    }
}

extern "C" void kernel_launch(void* const* d_in, const int* in_sizes, int n_in,
                              void* d_out, int out_size, void* d_ws, size_t ws_size,
                              hipStream_t stream)
{
    const float* x     = (const float*)d_in[0];
    const float* wq    = (const float*)d_in[1];
    const float* bq    = (const float*)d_in[2];
    const float* wk    = (const float*)d_in[3];
    const float* bk    = (const float*)d_in[4];
    const float* wv    = (const float*)d_in[5];
    const float* bv    = (const float*)d_in[6];
    const float* w_out = (const float*)d_in[7];
    const float* b_out = (const float*)d_in[8];
    const float* rw1 = (const float*)d_in[9];
    const float* rb1 = (const float*)d_in[10];
    const float* rga = (const float*)d_in[11];
    const float* rbe = (const float*)d_in[12];
    const float* rw2 = (const float*)d_in[13];
    const float* rb2 = (const float*)d_in[14];
    const float* cw1 = (const float*)d_in[15];
    const float* cb1 = (const float*)d_in[16];
    const float* cga = (const float*)d_in[17];
    const float* cbe = (const float*)d_in[18];
    const float* cw2 = (const float*)d_in[19];
    const float* cb2 = (const float*)d_in[20];
    // d_in[21]/d_in[22] (ridx/cidx) unused: closed-form rotation indices.

    float* Q   = (float*)d_ws;               // 2 x 401408 f32 + tables + Vfrag f16
    float* K   = Q + 401408;
    float* Etr = K + 401408;                 // 880 floats
    float* Etc = Etr + 880;                  // 880 floats
    _Float16* Vfrag = (_Float16*)(Etc + 880);// 32*25*64*8 = 409600 halves (16B-aligned)

    prep_kernel<<<1570, 256, 0, stream>>>(x, wq, bq, wk, bk, wv, bv, b_out,
                                          rw1, rb1, rga, rbe, rw2, rb2,
                                          cw1, cb1, cga, cbe, cw2, cb2,
                                          Q, K, Vfrag, Etr, Etc, (float*)d_out);
    attn_kernel<<<8 * NPOS, 256, 0, stream>>>(
        Q, K, Vfrag, Etr, Etc, w_out, (float*)d_out);
}

// Round 2
// 259.077 us; speedup vs baseline: 1.0853x; 1.0853x over previous
//
#include <hip/hip_runtime.h>
#include <hip/hip_bf16.h>
#include <hip/hip_fp16.h>

#define NPOS 784
#define WDIM 28

typedef _Float16 f16x8 __attribute__((ext_vector_type(8)));
typedef float    f32x4 __attribute__((ext_vector_type(4)));

// ---------------- kernel 1: merged embed + qkv ----------------
// Blocks 0..1567: fused 1x1-conv q/k/v. Q,K fp32 [bh][kl][m]; V as f16 MFMA
//                 B-fragments [bh][step(26)][lane][8] (lane = (kk>>3)<<4 | m).
// Block 1568: embedding-MLP tables Etr/Etc (transposed [m][110]).
// Block 1569: zero the Vfrag key-pad region (keys 784..831).
__global__ __launch_bounds__(256) void prep_kernel(
    const float* __restrict__ x,
    const float* __restrict__ wq, const float* __restrict__ bq,
    const float* __restrict__ wk, const float* __restrict__ bk,
    const float* __restrict__ wv, const float* __restrict__ bv,
    const float* __restrict__ rw1, const float* __restrict__ rb1,
    const float* __restrict__ rga, const float* __restrict__ rbe,
    const float* __restrict__ rw2, const float* __restrict__ rb2,
    const float* __restrict__ cw1, const float* __restrict__ cb1,
    const float* __restrict__ cga, const float* __restrict__ cbe,
    const float* __restrict__ cw2, const float* __restrict__ cb2,
    float* __restrict__ Q, float* __restrict__ K, _Float16* __restrict__ Vfrag,
    float* __restrict__ Etr, float* __restrict__ Etc)
{
    if (blockIdx.x == 1568) {                        // ---- embed path ----
        int t = threadIdx.x;
        int d = -1;
        const float *w1 = rw1, *b1 = rb1, *ga = rga, *be = rbe, *w2 = rw2, *b2 = rb2;
        float* E = Etr;
        if (t < 110) { d = t; }
        else if (t >= 128 && t < 238) { d = t - 128; w1 = cw1; b1 = cb1; ga = cga; be = cbe; w2 = cw2; b2 = cb2; E = Etc; }
        if (d < 0) return;
        float u = (d < 55) ? (-1.0f + (float)d * (2.0f / 54.0f))
                           : -(-1.0f + (float)(d - 55) * (2.0f / 54.0f));
        float hb[16], mu = 0.0f;
#pragma unroll
        for (int c = 0; c < 16; ++c) { hb[c] = u * w1[c] + b1[c]; mu += hb[c]; }
        mu *= (1.0f / 16.0f);
        float var = 0.0f;
#pragma unroll
        for (int c = 0; c < 16; ++c) { float dv = hb[c] - mu; var += dv * dv; }
        var *= (1.0f / 16.0f);
        float rstd = rsqrtf(var + 1e-5f);
#pragma unroll
        for (int c = 0; c < 16; ++c) {
            float hn = ga[c] * (hb[c] - mu) * rstd + be[c];
            hb[c] = hn / (1.0f + __expf(-hn));
        }
#pragma unroll
        for (int m = 0; m < 8; ++m) {
            float e = b2[m];
#pragma unroll
            for (int c = 0; c < 16; ++c) e += hb[c] * w2[m * 16 + c];
            E[m * 110 + d] = e;
        }
        return;
    }

    if (blockIdx.x == 1569) {                        // ---- Vfrag pad-zero path ----
        // pad keys 784..831: step 24 fragment-lanes 32..63 + step 25 all lanes,
        // per bh: 128 + 256 uints. Zero so pad-P (=0) x pad-V never makes NaN.
        unsigned int* pz = (unsigned int*)Vfrag;
        for (int e = threadIdx.x; e < 32 * 384; e += 256) {
            int bh = e / 384, r = e - bh * 384;
            int idx;
            if (r < 128) idx = ((bh * 26 + 24) * 64 + 32 + (r >> 2)) * 4 + (r & 3);
            else { int rr = r - 128; idx = ((bh * 26 + 25) * 64 + (rr >> 2)) * 4 + (rr & 3); }
            pz[idx] = 0u;
        }
        return;
    }

    // ---- qkv path ----
    int idx = blockIdx.x * 256 + threadIdx.x;        // covers exactly 401408
    int ij = idx % NPOS;
    int oc = (idx / NPOS) & 127;
    int b  = idx / (NPOS * 128);

    float x0 = x[(b * 3 + 0) * NPOS + ij];
    float x1 = x[(b * 3 + 1) * NPOS + ij];
    float x2 = x[(b * 3 + 2) * NPOS + ij];

    float q = bq[oc] + wq[oc*3+0]*x0 + wq[oc*3+1]*x1 + wq[oc*3+2]*x2;
    float k = bk[oc] + wk[oc*3+0]*x0 + wk[oc*3+1]*x1 + wk[oc*3+2]*x2;
    float v = bv[oc] + wv[oc*3+0]*x0 + wv[oc*3+1]*x1 + wv[oc*3+2]*x2;

    int m = oc >> 3, h = oc & 7;                     // oc = m*HEADS + h
    int dst = ((b * 8 + h) * NPOS + ij) * 16 + m;
    Q[dst] = q; K[dst] = k;

    // V in MFMA B-fragment order: B[k][m], lane = (kslot>>3)<<4 | m, j = kslot&7
    {
        int s5 = ij >> 5, kk = ij & 31;
        int fl = ((kk >> 3) << 4) | m;
        Vfrag[((((b * 8 + h) * 26 + s5) * 64 + fl) << 3) + (kk & 7)] = (_Float16)v;
    }
}

// ---------------- kernel 2: attention, 8 heads per block (512 threads) ----------------
// Grid = 3136 blocks (b, ij), XCD-chunked swizzle. One head per wave.
// Changes vs r1: (1) pass B/C interleaved in 13 chunks of 64 keys -> ptile
// shrinks 25.6KB -> 640B/wave, LDS 30.2 -> 14.4KB, occupancy 50% -> 100%;
// (2) both head-groups in one block -> plain stores, no atomics, no out-init.
__global__ __launch_bounds__(512, 8) void attn_kernel(
    const float* __restrict__ Q, const float* __restrict__ K,
    const _Float16* __restrict__ Vfrag,
    const float* __restrict__ Etr, const float* __restrict__ Etc,
    const float* __restrict__ w_out, const float* __restrict__ b_out,
    float* __restrict__ out)
{
    __shared__ float4 RtE[8][56];                         // exp'ed rotation terms / wave
    __shared__ __align__(16) _Float16 ptile[8][320];      // [wave][g*80 + k], 64 keys/chunk
    __shared__ float ovs[4 * 132];                        // [g][m*8+h], g-stride 132

    const int t    = threadIdx.x;
    const int wave = t >> 6, lane = t & 63;
    // XCD-chunked decode: each XCD owns a contiguous run of (b, ij)
    const int bid = blockIdx.x;
    const int g   = (bid & 7) * 392 + (bid >> 3);         // bijective, 3136 = 8*392
    const int b   = g / 784;
    const int ij  = g - b * 784;
    const int iq  = ij / WDIM, jq = ij % WDIM;
    const int bh  = b * 8 + wave;                         // head = wave
    const float scale = 0.57735026918962576f;             // 1/sqrt(CIN=3)

    // q in registers (wave-uniform loads, L2-hot)
    float q[16];
    {
        const float4* qp = (const float4*)(Q + (size_t)(bh * NPOS + ij) * 16);
        float4 q0 = qp[0], q1 = qp[1], q2 = qp[2], q3 = qp[3];
        q[0]=q0.x; q[1]=q0.y; q[2]=q0.z; q[3]=q0.w;
        q[4]=q1.x; q[5]=q1.y; q[6]=q1.z; q[7]=q1.w;
        q[8]=q2.x; q[9]=q2.y; q[10]=q2.z; q[11]=q2.w;
        q[12]=q3.x; q[13]=q3.y; q[14]=q3.z; q[15]=q3.w;
    }

    // rotation terms from global tables -> exp'ed
    {
        float4 mine = make_float4(-3.0e38f, -3.0e38f, -3.0e38f, -3.0e38f);
        float4 rv   = mine;
        if (lane < 55) {
            float ar = 0, ac = 0, ar5 = 0, ac5 = 0;
#pragma unroll
            for (int mm = 0; mm < 8; ++mm) {
                float ql = q[mm], qh = q[8 + mm];
                ar  += ql * Etr[mm * 110 + lane];
                ar5 += ql * Etr[mm * 110 + lane + 55];
                ac  += qh * Etc[mm * 110 + lane];
                ac5 += qh * Etc[mm * 110 + lane + 55];
            }
            rv = make_float4(ar * scale, ac * scale, ar5 * scale, ac5 * scale);
            mine = rv;
        }
#pragma unroll
        for (int off = 1; off < 64; off <<= 1) {
            mine.x = fmaxf(mine.x, __shfl_xor(mine.x, off, 64));
            mine.y = fmaxf(mine.y, __shfl_xor(mine.y, off, 64));
            mine.z = fmaxf(mine.z, __shfl_xor(mine.z, off, 64));
            mine.w = fmaxf(mine.w, __shfl_xor(mine.w, off, 64));
        }
        if (lane < 55)
            RtE[wave][lane] = make_float4(__expf(rv.x - mine.x), __expf(rv.y - mine.y),
                                          __expf(rv.z - mine.z), __expf(rv.w - mine.w));
    }

    // pass A: content in registers; track max
    float creg[13];
    float maxc = -3.0e38f;
#pragma unroll
    for (int it = 0; it < 13; ++it) {
        int k = it * 64 + lane;
        creg[it] = 0.0f;
        if (k < NPOS) {
            const float4* kp = (const float4*)(K + (size_t)(bh * NPOS + k) * 16);
            float4 k0 = kp[0], k1 = kp[1], k2 = kp[2], k3 = kp[3];
            float c = q[0]*k0.x + q[1]*k0.y + q[2]*k0.z + q[3]*k0.w
                    + q[4]*k1.x + q[5]*k1.y + q[6]*k1.z + q[7]*k1.w
                    + q[8]*k2.x + q[9]*k2.y + q[10]*k2.z + q[11]*k2.w
                    + q[12]*k3.x + q[13]*k3.y + q[14]*k3.z + q[15]*k3.w;
            creg[it] = c * scale;
            maxc = fmaxf(maxc, creg[it]);
        }
    }
#pragma unroll
    for (int off = 1; off < 64; off <<= 1) maxc = fmaxf(maxc, __shfl_xor(maxc, off, 64));

    // pass B+C interleaved: per 64-key chunk, compute p -> tiny LDS tile ->
    // 2x v_mfma_f32_16x16x32_f16. No barriers (ptile is wave-private).
    // A rows 0..3 = g (rows 4..15 zero); B = prebuilt Vfrag (lane*16B coalesced).
    float ps0 = 0, ps1 = 0, ps2 = 0, ps3 = 0;
    f32x4 d = {0.0f, 0.0f, 0.0f, 0.0f};
    {
        const int g15 = lane & 15, kg = lane >> 4;
        _Float16* pt = &ptile[wave][0];                   // rows at g*80 halves
        const _Float16* ar0 = &ptile[wave][g15 * 80 + kg * 8];
        const f16x8* vp = (const f16x8*)(Vfrag + ((size_t)bh * 26 * 64 + lane) * 8);
#pragma unroll
        for (int c = 0; c < 13; ++c) {
            int k = c * 64 + lane;
            float p0 = 0.0f, p1 = 0.0f, p2 = 0.0f, p3 = 0.0f;
            if (k < NPOS) {
                float ec = __expf(creg[c] - maxc);
                int rk = (k * 2341) >> 16;                // k / 28 (exact for k < 784)
                int ck = k - rk * WDIM;
                float4 er = RtE[wave][rk - iq + 27];
                float4 el = RtE[wave][ck - jq + 27];
                p0 = ec * er.x * el.y;
                p1 = ec * er.y * el.z;
                p2 = ec * er.z * el.w;
                p3 = ec * er.w * el.x;
                ps0 += p0; ps1 += p1; ps2 += p2; ps3 += p3;
            }
            pt[0 * 80 + lane] = (_Float16)p0;             // pad keys write exact zeros
            pt[1 * 80 + lane] = (_Float16)p1;
            pt[2 * 80 + lane] = (_Float16)p2;
            pt[3 * 80 + lane] = (_Float16)p3;
#pragma unroll
            for (int s2 = 0; s2 < 2; ++s2) {
                f16x8 a = {};
                if (g15 < 4) a = *(const f16x8*)(ar0 + s2 * 32);
                f16x8 bf = vp[(c * 2 + s2) * 64];
                d = __builtin_amdgcn_mfma_f32_16x16x32_f16(a, bf, d, 0, 0, 0);
            }
        }
    }
#pragma unroll
    for (int off = 1; off < 64; off <<= 1) {
        ps0 += __shfl_xor(ps0, off, 64); ps1 += __shfl_xor(ps1, off, 64);
        ps2 += __shfl_xor(ps2, off, 64); ps3 += __shfl_xor(ps3, off, 64);
    }

    // D layout (verified): col=lane&15 (=m), row=(lane>>4)*4+reg (=g) -> lanes 0..15
    if ((lane >> 4) == 0) {
        float i0 = 1.0f / ps0, i1 = 1.0f / ps1, i2 = 1.0f / ps2, i3 = 1.0f / ps3;
        ovs[0 * 132 + lane * 8 + wave] = d[0] * i0;
        ovs[1 * 132 + lane * 8 + wave] = d[1] * i1;
        ovs[2 * 132 + lane * 8 + wave] = d[2] * i2;
        ovs[3 * 132 + lane * 8 + wave] = d[3] * i3;
    }
    __syncthreads();                                      // all 8 heads ready

    // output projection over all 16 m x 8 h; thread = (o = t>>2, g = t&3), t < 256
    if (t < 256) {
        int o = t >> 2, gg = t & 3;
        float a = 0.0f;
#pragma unroll
        for (int i = 0; i < 32; ++i) {
            float4 w4 = *(const float4*)(w_out + o * 128 + i * 4);
            float4 ov = *(const float4*)(ovs + gg * 132 + i * 4);
            a += w4.x * ov.x + w4.y * ov.y + w4.z * ov.z + w4.w * ov.w;
        }
        out[((size_t)(b * 64 + o) * 4 + gg) * NPOS + ij] = a + b_out[o];
    }
}

extern "C" void kernel_launch(void* const* d_in, const int* in_sizes, int n_in,
                              void* d_out, int out_size, void* d_ws, size_t ws_size,
                              hipStream_t stream)
{
    const float* x     = (const float*)d_in[0];
    const float* wq    = (const float*)d_in[1];
    const float* bq    = (const float*)d_in[2];
    const float* wk    = (const float*)d_in[3];
    const float* bk    = (const float*)d_in[4];
    const float* wv    = (const float*)d_in[5];
    const float* bv    = (const float*)d_in[6];
    const float* w_out = (const float*)d_in[7];
    const float* b_out = (const float*)d_in[8];
    const float* rw1 = (const float*)d_in[9];
    const float* rb1 = (const float*)d_in[10];
    const float* rga = (const float*)d_in[11];
    const float* rbe = (const float*)d_in[12];
    const float* rw2 = (const float*)d_in[13];
    const float* rb2 = (const float*)d_in[14];
    const float* cw1 = (const float*)d_in[15];
    const float* cb1 = (const float*)d_in[16];
    const float* cga = (const float*)d_in[17];
    const float* cbe = (const float*)d_in[18];
    const float* cw2 = (const float*)d_in[19];
    const float* cb2 = (const float*)d_in[20];
    // d_in[21]/d_in[22] (ridx/cidx) unused: closed-form rotation indices.

    float* Q   = (float*)d_ws;               // 2 x 401408 f32 + tables + Vfrag f16
    float* K   = Q + 401408;
    float* Etr = K + 401408;                 // 880 floats
    float* Etc = Etr + 880;                  // 880 floats
    _Float16* Vfrag = (_Float16*)(Etc + 880);// 32*26*64*8 = 425984 halves (16B-aligned)

    prep_kernel<<<1570, 256, 0, stream>>>(x, wq, bq, wk, bk, wv, bv,
                                          rw1, rb1, rga, rbe, rw2, rb2,
                                          cw1, cb1, cga, cbe, cw2, cb2,
                                          Q, K, Vfrag, Etr, Etc);
    attn_kernel<<<4 * NPOS, 512, 0, stream>>>(
        Q, K, Vfrag, Etr, Etc, w_out, b_out, (float*)d_out);
}